// Round 2
// baseline (2193.890 us; speedup 1.0000x reference)
//
#include <hip/hip_runtime.h>
#include <hip/hip_bf16.h>
#include <math.h>

// Problem: B=8, P=1024, DIM=768, H=12, KV=6, GS=2, HD=64
// out = proj( GQA_attention(x) - (Z*r_std + r_mean) ) where Z is a fixed
// standardized jax.random.uniform(key(42),(6,2,65536)) field.
//
// Z PRNG: JAX >=0.4.36 defaults jax_threefry_partitionable=True:
//   per flat element i: (o0,o1) = threefry2x32(key=(0,42), x=(hi32(i), lo32(i)))
//   bits = o0 ^ o1; u = bitcast((bits>>9)|0x3f800000) - 1
// (R1 used the legacy split-halves scheme -> uncorrelated Z -> absmax 0.445.)
//
// Round 2: fp32 correctness baseline with partitionable Threefry.
//   ws layout (floats): qb[8192*768] kb[8192*384] vb[8192*384] attb[8192*768]
//                       zb[786432] zpart[192]   total ~78.6 MB

#define NTHREADS 256

// ---------------- Threefry-2x32, key = (0, 42) -------------------------------
__device__ __forceinline__ unsigned rotl_u32(unsigned x, int r) {
    return (x << r) | (x >> (32 - r));
}

__device__ __forceinline__ void threefry_0_42(unsigned x0, unsigned x1,
                                              unsigned& o0, unsigned& o1) {
    const unsigned ks0 = 0u, ks1 = 42u, ks2 = 0u ^ 42u ^ 0x1BD11BDAu;
    x0 += ks0; x1 += ks1;
#define R4(a,b,c,d) \
    x0 += x1; x1 = rotl_u32(x1,a); x1 ^= x0; \
    x0 += x1; x1 = rotl_u32(x1,b); x1 ^= x0; \
    x0 += x1; x1 = rotl_u32(x1,c); x1 ^= x0; \
    x0 += x1; x1 = rotl_u32(x1,d); x1 ^= x0;
    R4(13,15,26,6)   x0 += ks1; x1 += ks2 + 1u;
    R4(17,29,16,24)  x0 += ks2; x1 += ks0 + 2u;
    R4(13,15,26,6)   x0 += ks0; x1 += ks1 + 3u;
    R4(17,29,16,24)  x0 += ks1; x1 += ks2 + 4u;
    R4(13,15,26,6)   x0 += ks2; x1 += ks0 + 5u;
#undef R4
    o0 = x0; o1 = x1;
}

// element i of jax.random.uniform(key(42), 786432 elems), partitionable path:
// counts = iota(uint64); x0 = hi32(i) = 0, x1 = lo32(i) = i; bits = o0 ^ o1.
__device__ __forceinline__ float tf_uniform(unsigned i) {
    unsigned o0, o1;
    threefry_0_42(0u, i, o0, o1);
    unsigned bits = o0 ^ o1;
    return __uint_as_float((bits >> 9) | 0x3f800000u) - 1.0f;
}

__device__ __forceinline__ float wave_sum64(float v) {
#pragma unroll
    for (int off = 32; off; off >>= 1) v += __shfl_xor(v, off, 64);
    return v;
}

// ---------------- Z kernels: M -> standardized Z, 12 rows of 65536 ------------
// z1: write M, per-chunk partial sums. 96 blocks = 12 rows x 8 chunks.
__global__ __launch_bounds__(NTHREADS) void z1_k(float* __restrict__ zb,
                                                 float* __restrict__ zpart) {
    int bh = blockIdx.x;
    int row = bh >> 3, chunk = bh & 7;
    int g = row & 1;               // diag zero at in-row index g
    int j0 = chunk * 8192;
    float sum = 0.f, sumsq = 0.f;
    for (int t = threadIdx.x; t < 8192; t += NTHREADS) {
        int j = j0 + t;
        unsigned i = (unsigned)row * 65536u + (unsigned)j;
        float m = tf_uniform(i);
        if (j == g) m = 0.f;
        zb[i] = m;
        sum += m; sumsq += m * m;
    }
    __shared__ float rbuf[8];
    sum = wave_sum64(sum); sumsq = wave_sum64(sumsq);
    int lane = threadIdx.x & 63, wv = threadIdx.x >> 6;
    if (lane == 0) { rbuf[wv] = sum; rbuf[4 + wv] = sumsq; }
    __syncthreads();
    if (threadIdx.x == 0) {
        zpart[bh * 2]     = rbuf[0] + rbuf[1] + rbuf[2] + rbuf[3];
        zpart[bh * 2 + 1] = rbuf[4] + rbuf[5] + rbuf[6] + rbuf[7];
    }
}

// z2: standardize in place (unbiased std, ddof=1)
__global__ __launch_bounds__(NTHREADS) void z2_k(float* __restrict__ zb,
                                                 const float* __restrict__ zpart) {
    int bh = blockIdx.x;
    int row = bh >> 3, chunk = bh & 7;
    float s = 0.f, s2 = 0.f;
    for (int c = 0; c < 8; ++c) {
        s  += zpart[(row * 8 + c) * 2];
        s2 += zpart[(row * 8 + c) * 2 + 1];
    }
    float mean = s * (1.f / 65536.f);
    float var  = (s2 - 65536.f * mean * mean) * (1.f / 65535.f);
    float sd   = sqrtf(fmaxf(var, 0.f));
    if (sd == 0.f) sd = 1.f;
    float rstd = 1.f / sd;
    int j0 = chunk * 8192;
    for (int t = threadIdx.x; t < 8192; t += NTHREADS) {
        unsigned i = (unsigned)row * 65536u + (unsigned)(j0 + t);
        zb[i] = (zb[i] - mean) * rstd;
    }
}

// ---------------- fp32 GEMM: C[M,N] = alpha * A[M,K] @ W[K,N] (+bias) ---------
// 128x128 tile, BK=8, 256 threads, 8x8 microtile.
__device__ __forceinline__ void gemm_body(
    const float* __restrict__ A, const float* __restrict__ W, float* __restrict__ C,
    int K, int lda, int ldw, int ldc, int row0, int col0, float alpha,
    const float* __restrict__ bias)
{
    __shared__ float As[8][128];
    __shared__ float Bs[8][128];
    const int tid = threadIdx.x;
    const int tx = tid & 15, ty = tid >> 4;
    float acc[8][8];
#pragma unroll
    for (int i = 0; i < 8; ++i)
#pragma unroll
        for (int j = 0; j < 8; ++j) acc[i][j] = 0.f;

    const int ar = tid >> 1;          // 0..127 (tile row)
    const int ak = (tid & 1) * 4;     // 0 or 4
    const int bk = tid >> 5;          // 0..7
    const int bn = (tid & 31) * 4;    // 0..124

    for (int k0 = 0; k0 < K; k0 += 8) {
        float4 a4 = *(const float4*)(A + (size_t)(row0 + ar) * lda + k0 + ak);
        float4 b4 = *(const float4*)(W + (size_t)(k0 + bk) * ldw + col0 + bn);
        __syncthreads();   // previous iter's reads done before overwrite
        As[ak + 0][ar] = a4.x; As[ak + 1][ar] = a4.y;
        As[ak + 2][ar] = a4.z; As[ak + 3][ar] = a4.w;
        *(float4*)&Bs[bk][bn] = b4;
        __syncthreads();
#pragma unroll
        for (int kk = 0; kk < 8; ++kk) {
            float av[8], bv[8];
            *(float4*)&av[0] = *(const float4*)&As[kk][ty * 8];
            *(float4*)&av[4] = *(const float4*)&As[kk][ty * 8 + 4];
            *(float4*)&bv[0] = *(const float4*)&Bs[kk][tx * 8];
            *(float4*)&bv[4] = *(const float4*)&Bs[kk][tx * 8 + 4];
#pragma unroll
            for (int i = 0; i < 8; ++i)
#pragma unroll
                for (int j = 0; j < 8; ++j) acc[i][j] += av[i] * bv[j];
        }
    }
#pragma unroll
    for (int i = 0; i < 8; ++i) {
        int row = row0 + ty * 8 + i;
#pragma unroll
        for (int j = 0; j < 8; ++j) {
            int col = col0 + tx * 8 + j;
            float v = acc[i][j] * alpha;
            if (bias) v += bias[col];
            C[(size_t)row * ldc + col] = v;
        }
    }
}

// fused q/k/v: grid.x = 12 n-blocks (6 q, 3 k, 3 v), grid.y = 64 m-blocks
__global__ __launch_bounds__(NTHREADS) void qkv_gemm_k(
    const float* __restrict__ x, const float* __restrict__ Wq,
    const float* __restrict__ Wk, const float* __restrict__ Wv,
    float* __restrict__ qb, float* __restrict__ kb, float* __restrict__ vb)
{
    int nb = blockIdx.x;
    int row0 = blockIdx.y * 128;
    const float* W; float* C; int N, col0; float alpha;
    if (nb < 6)      { W = Wq; C = qb; N = 768; col0 = nb * 128;       alpha = 0.125f; } // q * HD^-0.5
    else if (nb < 9) { W = Wk; C = kb; N = 384; col0 = (nb - 6) * 128; alpha = 1.0f; }
    else             { W = Wv; C = vb; N = 384; col0 = (nb - 9) * 128; alpha = 1.0f; }
    gemm_body(x, W, C, 768, 768, N, N, row0, col0, alpha, nullptr);
}

__global__ __launch_bounds__(NTHREADS) void proj_gemm_k(
    const float* __restrict__ attb, const float* __restrict__ Wp,
    const float* __restrict__ bp, float* __restrict__ out)
{
    gemm_body(attb, Wp, out, 768, 768, 768, 768,
              blockIdx.y * 128, blockIdx.x * 128, 1.0f, bp);
}

// ---------------- attention: 8 q-rows per block, full 1024-key two-pass ------
// grid = B*H*(P/8) = 12288 blocks. LDS: qs 2K + sc 32K + red3 8K ~ 43KB
__global__ __launch_bounds__(NTHREADS) void attn_k(
    const float* __restrict__ qb, const float* __restrict__ kb,
    const float* __restrict__ vb, float* __restrict__ attb)
{
    __shared__ float qs[8][64];
    __shared__ float sc[8][1024];
    __shared__ float rs[8];
    __shared__ float red3[4][8][64];

    int bx = blockIdx.x;
    int qt = bx & 127;
    int h  = (bx >> 7) % 12;
    int b  = bx / 1536;
    int kv = h >> 1;
    int tid = threadIdx.x;
    int lane = tid & 63, wv = tid >> 6;

    if (tid < 128) {  // 512 floats of q
        int r = tid >> 4, dq = (tid & 15) * 4;
        *(float4*)&qs[r][dq] =
            *(const float4*)(qb + ((size_t)(b * 1024 + qt * 8 + r)) * 768 + h * 64 + dq);
    }
    __syncthreads();

    // phase 1: scores sc[r][j] = q[r] . k[j]   (scale pre-folded into q)
    {
        const float* kpbase = kb + ((size_t)b * 1024) * 384 + (size_t)kv * 64;
#pragma unroll 1
        for (int ch = 0; ch < 4; ++ch) {
            int j = ch * 256 + tid;
            float kreg[64];
            const float* kp = kpbase + (size_t)j * 384;
#pragma unroll
            for (int ii = 0; ii < 16; ++ii)
                *(float4*)&kreg[ii * 4] = *(const float4*)(kp + ii * 4);
#pragma unroll
            for (int r = 0; r < 8; ++r) {
                float s = 0.f;
#pragma unroll
                for (int d = 0; d < 64; d += 4) {
                    float4 q4 = *(const float4*)&qs[r][d];
                    s += q4.x * kreg[d] + q4.y * kreg[d + 1]
                       + q4.z * kreg[d + 2] + q4.w * kreg[d + 3];
                }
                sc[r][j] = s;
            }
        }
    }
    __syncthreads();

    // phase 2: softmax (unnormalized exp stored; 1/sum in rs). 32 lanes per row.
    {
        int r = tid >> 5, t32 = tid & 31;
        float m = -1e30f;
        for (int j = t32; j < 1024; j += 32) m = fmaxf(m, sc[r][j]);
#pragma unroll
        for (int off = 16; off; off >>= 1) m = fmaxf(m, __shfl_xor(m, off, 32));
        float sum = 0.f;
        for (int j = t32; j < 1024; j += 32) {
            float e = __expf(sc[r][j] - m);
            sc[r][j] = e;
            sum += e;
        }
#pragma unroll
        for (int off = 16; off; off >>= 1) sum += __shfl_xor(sum, off, 32);
        if (t32 == 0) rs[r] = 1.f / sum;
    }
    __syncthreads();

    // phase 3: att[r][d] = sum_j w[r][j] * v[j][d]; wave wv owns keys wv*256..+255
    float acc[8] = {0.f, 0.f, 0.f, 0.f, 0.f, 0.f, 0.f, 0.f};
    {
        const float* vbase = vb + ((size_t)b * 1024) * 384 + (size_t)kv * 64 + lane;
        for (int jj = 0; jj < 64; ++jj) {
            int j = wv * 256 + jj * 4;
            float v0 = vbase[(size_t)(j + 0) * 384];
            float v1 = vbase[(size_t)(j + 1) * 384];
            float v2 = vbase[(size_t)(j + 2) * 384];
            float v3 = vbase[(size_t)(j + 3) * 384];
#pragma unroll
            for (int r = 0; r < 8; ++r) {
                float4 w4 = *(const float4*)&sc[r][j];
                acc[r] += w4.x * v0 + w4.y * v1 + w4.z * v2 + w4.w * v3;
            }
        }
    }
#pragma unroll
    for (int r = 0; r < 8; ++r) red3[wv][r][lane] = acc[r];
    __syncthreads();
    for (int o = tid; o < 512; o += NTHREADS) {
        int r = o >> 6, d = o & 63;
        float a = (red3[0][r][d] + red3[1][r][d] + red3[2][r][d] + red3[3][r][d]) * rs[r];
        attb[((size_t)(b * 1024 + qt * 8 + r)) * 768 + h * 64 + d] = a;
    }
}

// ---------------- per-(b,h) stats + noise subtraction, in place --------------
// flat[b,h,:] -= Z[h,:]*r_std + r_mean   over y = p*64+d (65536 elems)
__global__ __launch_bounds__(NTHREADS) void stats_norm_k(
    float* __restrict__ attb, const float* __restrict__ zb)
{
    int bh = blockIdx.x;
    int b = bh / 12, h = bh % 12;
    float* base = attb + ((size_t)b * 1024) * 768 + h * 64;
    float sum = 0.f, sumsq = 0.f;
    for (int f = threadIdx.x; f < 16384; f += NTHREADS) {   // float4 index
        int p = f >> 4, dq = (f & 15) * 4;
        float4 a = *(const float4*)(base + (size_t)p * 768 + dq);
        sum   += a.x + a.y + a.z + a.w;
        sumsq += a.x * a.x + a.y * a.y + a.z * a.z + a.w * a.w;
    }
    __shared__ float rbuf[8];
    sum = wave_sum64(sum); sumsq = wave_sum64(sumsq);
    int lane = threadIdx.x & 63, wv = threadIdx.x >> 6;
    if (lane == 0) { rbuf[wv] = sum; rbuf[4 + wv] = sumsq; }
    __syncthreads();
    sum   = rbuf[0] + rbuf[1] + rbuf[2] + rbuf[3];
    sumsq = rbuf[4] + rbuf[5] + rbuf[6] + rbuf[7];
    float mean = sum * (1.f / 65536.f);
    float var  = (sumsq - 65536.f * mean * mean) * (1.f / 65535.f);
    float sd   = sqrtf(fmaxf(var, 0.f));   // no zero-guard (matches reference)
    const float* zrow = zb + (size_t)h * 65536;
    for (int f = threadIdx.x; f < 16384; f += NTHREADS) {
        int p = f >> 4, dq = (f & 15) * 4;
        float4 a = *(const float4*)(base + (size_t)p * 768 + dq);
        float4 z = *(const float4*)(zrow + (size_t)f * 4);
        a.x -= z.x * sd + mean;
        a.y -= z.y * sd + mean;
        a.z -= z.z * sd + mean;
        a.w -= z.w * sd + mean;
        *(float4*)(base + (size_t)p * 768 + dq) = a;
    }
}

extern "C" void kernel_launch(void* const* d_in, const int* in_sizes, int n_in,
                              void* d_out, int out_size, void* d_ws, size_t ws_size,
                              hipStream_t stream) {
    const float* x  = (const float*)d_in[0];
    const float* Wq = (const float*)d_in[1];
    const float* Wk = (const float*)d_in[2];
    const float* Wv = (const float*)d_in[3];
    const float* Wp = (const float*)d_in[4];
    const float* bp = (const float*)d_in[5];
    float* out = (float*)d_out;

    float* ws    = (float*)d_ws;
    float* qb    = ws;                    // 8192*768
    float* kb    = qb + 6291456;          // 8192*384
    float* vb    = kb + 3145728;          // 8192*384
    float* attb  = vb + 3145728;          // 8192*768
    float* zb    = attb + 6291456;        // 12*65536
    float* zpart = zb + 786432;           // 96*2

    z1_k<<<96, NTHREADS, 0, stream>>>(zb, zpart);
    z2_k<<<96, NTHREADS, 0, stream>>>(zb, zpart);
    qkv_gemm_k<<<dim3(12, 64), NTHREADS, 0, stream>>>(x, Wq, Wk, Wv, qb, kb, vb);
    attn_k<<<12288, NTHREADS, 0, stream>>>(qb, kb, vb, attb);
    stats_norm_k<<<96, NTHREADS, 0, stream>>>(attb, zb);
    proj_gemm_k<<<dim3(6, 64), NTHREADS, 0, stream>>>(attb, Wp, bp, out);
}

// Round 3
// 638.655 us; speedup vs baseline: 3.4352x; 3.4352x over previous
//
#include <hip/hip_runtime.h>
#include <hip/hip_bf16.h>
#include <math.h>

// B=8, P=1024, DIM=768, H=12, KV=6, GS=2, HD=64
// R3: bf16-MFMA flash attention (wave-private online softmax), fp32 GEMMs.
// ws (floats): attb[6291456] zb[786432] zpart[192]
//              then ushort: qbh[6291456] kbh[3145728] vbt[3145728]

#define NTHREADS 256

typedef __bf16 bf16x8 __attribute__((ext_vector_type(8)));
typedef float f32x4 __attribute__((ext_vector_type(4)));

#define MFMA16(a, b, c) __builtin_amdgcn_mfma_f32_16x16x32_bf16(a, b, c, 0, 0, 0)

// ---------------- Threefry-2x32 partitionable, key=(0,42) --------------------
__device__ __forceinline__ unsigned rotl_u32(unsigned x, int r) {
    return (x << r) | (x >> (32 - r));
}
__device__ __forceinline__ void threefry_0_42(unsigned x0, unsigned x1,
                                              unsigned& o0, unsigned& o1) {
    const unsigned ks0 = 0u, ks1 = 42u, ks2 = 0u ^ 42u ^ 0x1BD11BDAu;
    x0 += ks0; x1 += ks1;
#define R4(a,b,c,d) \
    x0 += x1; x1 = rotl_u32(x1,a); x1 ^= x0; \
    x0 += x1; x1 = rotl_u32(x1,b); x1 ^= x0; \
    x0 += x1; x1 = rotl_u32(x1,c); x1 ^= x0; \
    x0 += x1; x1 = rotl_u32(x1,d); x1 ^= x0;
    R4(13,15,26,6)   x0 += ks1; x1 += ks2 + 1u;
    R4(17,29,16,24)  x0 += ks2; x1 += ks0 + 2u;
    R4(13,15,26,6)   x0 += ks0; x1 += ks1 + 3u;
    R4(17,29,16,24)  x0 += ks1; x1 += ks2 + 4u;
    R4(13,15,26,6)   x0 += ks2; x1 += ks0 + 5u;
#undef R4
    o0 = x0; o1 = x1;
}
__device__ __forceinline__ float tf_uniform(unsigned i) {
    unsigned o0, o1;
    threefry_0_42(0u, i, o0, o1);
    unsigned bits = o0 ^ o1;
    return __uint_as_float((bits >> 9) | 0x3f800000u) - 1.0f;
}

__device__ __forceinline__ float wave_sum64(float v) {
#pragma unroll
    for (int off = 32; off; off >>= 1) v += __shfl_xor(v, off, 64);
    return v;
}

__device__ __forceinline__ unsigned short bf16_rne(float x) {
    unsigned u = __float_as_uint(x);
    return (unsigned short)((u + 0x7fffu + ((u >> 16) & 1u)) >> 16);
}
__device__ __forceinline__ unsigned pack_bf16x2(float lo, float hi) {
    return (unsigned)bf16_rne(lo) | ((unsigned)bf16_rne(hi) << 16);
}

// ---------------- Z kernels --------------------------------------------------
__global__ __launch_bounds__(NTHREADS) void z1_k(float* __restrict__ zb,
                                                 float* __restrict__ zpart) {
    int bh = blockIdx.x;
    int row = bh >> 3, chunk = bh & 7;
    int g = row & 1;
    int j0 = chunk * 8192;
    float sum = 0.f, sumsq = 0.f;
    for (int t = threadIdx.x; t < 8192; t += NTHREADS) {
        int j = j0 + t;
        unsigned i = (unsigned)row * 65536u + (unsigned)j;
        float m = tf_uniform(i);
        if (j == g) m = 0.f;
        zb[i] = m;
        sum += m; sumsq += m * m;
    }
    __shared__ float rbuf[8];
    sum = wave_sum64(sum); sumsq = wave_sum64(sumsq);
    int lane = threadIdx.x & 63, wv = threadIdx.x >> 6;
    if (lane == 0) { rbuf[wv] = sum; rbuf[4 + wv] = sumsq; }
    __syncthreads();
    if (threadIdx.x == 0) {
        zpart[bh * 2]     = rbuf[0] + rbuf[1] + rbuf[2] + rbuf[3];
        zpart[bh * 2 + 1] = rbuf[4] + rbuf[5] + rbuf[6] + rbuf[7];
    }
}

__global__ __launch_bounds__(NTHREADS) void z2_k(float* __restrict__ zb,
                                                 const float* __restrict__ zpart) {
    int bh = blockIdx.x;
    int row = bh >> 3, chunk = bh & 7;
    float s = 0.f, s2 = 0.f;
    for (int c = 0; c < 8; ++c) {
        s  += zpart[(row * 8 + c) * 2];
        s2 += zpart[(row * 8 + c) * 2 + 1];
    }
    float mean = s * (1.f / 65536.f);
    float var  = (s2 - 65536.f * mean * mean) * (1.f / 65535.f);
    float sd   = sqrtf(fmaxf(var, 0.f));
    if (sd == 0.f) sd = 1.f;
    float rstd = 1.f / sd;
    int j0 = chunk * 8192;
    for (int t = threadIdx.x; t < 8192; t += NTHREADS) {
        unsigned i = (unsigned)row * 65536u + (unsigned)(j0 + t);
        zb[i] = (zb[i] - mean) * rstd;
    }
}

// ---------------- fp32 GEMM body (proj) --------------------------------------
__device__ __forceinline__ void gemm_compute(
    const float* __restrict__ A, const float* __restrict__ W,
    int K, int lda, int ldw, int row0, int col0, float acc[8][8])
{
    __shared__ float As[8][128];
    __shared__ float Bs[8][128];
    const int tid = threadIdx.x;
#pragma unroll
    for (int i = 0; i < 8; ++i)
#pragma unroll
        for (int j = 0; j < 8; ++j) acc[i][j] = 0.f;

    const int tx = tid & 15, ty = tid >> 4;
    const int ar = tid >> 1;
    const int ak = (tid & 1) * 4;
    const int bk = tid >> 5;
    const int bn = (tid & 31) * 4;

    for (int k0 = 0; k0 < K; k0 += 8) {
        float4 a4 = *(const float4*)(A + (size_t)(row0 + ar) * lda + k0 + ak);
        float4 b4 = *(const float4*)(W + (size_t)(k0 + bk) * ldw + col0 + bn);
        __syncthreads();
        As[ak + 0][ar] = a4.x; As[ak + 1][ar] = a4.y;
        As[ak + 2][ar] = a4.z; As[ak + 3][ar] = a4.w;
        *(float4*)&Bs[bk][bn] = b4;
        __syncthreads();
#pragma unroll
        for (int kk = 0; kk < 8; ++kk) {
            float av[8], bv[8];
            *(float4*)&av[0] = *(const float4*)&As[kk][ty * 8];
            *(float4*)&av[4] = *(const float4*)&As[kk][ty * 8 + 4];
            *(float4*)&bv[0] = *(const float4*)&Bs[kk][tx * 8];
            *(float4*)&bv[4] = *(const float4*)&Bs[kk][tx * 8 + 4];
#pragma unroll
            for (int i = 0; i < 8; ++i)
#pragma unroll
                for (int j = 0; j < 8; ++j) acc[i][j] += av[i] * bv[j];
        }
    }
}

// qkv: fp32 compute, bf16 head-separated outputs (v transposed)
// grid.x: 0..5 q-cols, 6..8 k-cols, 9..11 v-cols; grid.y: 64 m-blocks
__global__ __launch_bounds__(NTHREADS) void qkv_gemm_k(
    const float* __restrict__ x, const float* __restrict__ Wq,
    const float* __restrict__ Wk, const float* __restrict__ Wv,
    unsigned short* __restrict__ qbh, unsigned short* __restrict__ kbh,
    unsigned short* __restrict__ vbt)
{
    int nb = blockIdx.x;
    int row0 = blockIdx.y * 128;
    const float* W; int col0; int ldw; float alpha; int mode;
    if (nb < 6)      { W = Wq; col0 = nb * 128;       ldw = 768; alpha = 0.125f; mode = 0; }
    else if (nb < 9) { W = Wk; col0 = (nb - 6) * 128; ldw = 384; alpha = 1.0f;   mode = 1; }
    else             { W = Wv; col0 = (nb - 9) * 128; ldw = 384; alpha = 1.0f;   mode = 2; }

    float acc[8][8];
    gemm_compute(x, W, 768, 768, ldw, row0, col0, acc);

    const int tx = threadIdx.x & 15, ty = threadIdx.x >> 4;
    int brow = row0 >> 10;            // batch (blocks never straddle batches)
    int p0 = (row0 & 1023) + ty * 8;

    if (mode == 2) {
        // v transposed: [b][kv][d][1024], pack 8 consecutive p per store
#pragma unroll
        for (int j = 0; j < 8; ++j) {
            int col = col0 + tx * 8 + j;
            int kv = col >> 6, d = col & 63;
            unsigned w0 = pack_bf16x2(acc[0][j], acc[1][j]);
            unsigned w1 = pack_bf16x2(acc[2][j], acc[3][j]);
            unsigned w2 = pack_bf16x2(acc[4][j], acc[5][j]);
            unsigned w3 = pack_bf16x2(acc[6][j], acc[7][j]);
            uint4 u = {w0, w1, w2, w3};
            *(uint4*)(vbt + (((size_t)brow * 6 + kv) * 64 + d) * 1024 + p0) = u;
        }
    } else {
        int col = col0 + tx * 8;
        unsigned short* dst;
        if (mode == 0) {
            int h = col >> 6, d0 = col & 63;
            dst = qbh + (((size_t)brow * 12 + h) * 1024 + p0) * 64 + d0;
        } else {
            int kv = col >> 6, d0 = col & 63;
            dst = kbh + (((size_t)brow * 6 + kv) * 1024 + p0) * 64 + d0;
        }
#pragma unroll
        for (int i = 0; i < 8; ++i) {
            unsigned w0 = pack_bf16x2(acc[i][0] * alpha, acc[i][1] * alpha);
            unsigned w1 = pack_bf16x2(acc[i][2] * alpha, acc[i][3] * alpha);
            unsigned w2 = pack_bf16x2(acc[i][4] * alpha, acc[i][5] * alpha);
            unsigned w3 = pack_bf16x2(acc[i][6] * alpha, acc[i][7] * alpha);
            uint4 u = {w0, w1, w2, w3};
            *(uint4*)(dst + (size_t)i * 64) = u;
        }
    }
}

__global__ __launch_bounds__(NTHREADS) void proj_gemm_k(
    const float* __restrict__ attb, const float* __restrict__ Wp,
    const float* __restrict__ bp, float* __restrict__ out)
{
    float acc[8][8];
    int row0 = blockIdx.y * 128, col0 = blockIdx.x * 128;
    gemm_compute(attb, Wp, 768, 768, 768, row0, col0, acc);
    const int tx = threadIdx.x & 15, ty = threadIdx.x >> 4;
#pragma unroll
    for (int i = 0; i < 8; ++i) {
        int row = row0 + ty * 8 + i;
#pragma unroll
        for (int j = 0; j < 8; ++j) {
            int col = col0 + tx * 8 + j;
            out[(size_t)row * 768 + col] = acc[i][j] + bp[col];
        }
    }
}

// ---------------- bf16 MFMA flash attention ----------------------------------
// grid (8 qtiles, 12 h, 8 b), 256 thr = 4 waves; wave owns 32 queries.
// S^T = K·Q^T per 128-key tile; online softmax in C-layout (stats in-lane +
// 2 shfl_xor); P -> wave-private LDS (bf16, pad 136); O accum in MFMA C regs.
#define LDP 136
__global__ __launch_bounds__(NTHREADS) void attn_mfma_k(
    const unsigned short* __restrict__ qbh, const unsigned short* __restrict__ kbh,
    const unsigned short* __restrict__ vbt, float* __restrict__ attb)
{
    __shared__ unsigned short P_lds[4 * 32 * LDP];   // 34816 B
    __shared__ float alpha_s[4][32];
    __shared__ float l_s[4][32];

    const int qt0 = blockIdx.x * 128;
    const int h = blockIdx.y, b = blockIdx.z, kv = h >> 1;
    const int tid = threadIdx.x;
    const int w = tid >> 6, lane = tid & 63;
    const int c = lane & 15, g = lane >> 4;

    const unsigned short* qh = qbh + (((size_t)b * 12 + h) * 1024 + qt0 + w * 32) * 64;
    const unsigned short* kh = kbh + (((size_t)b * 6 + kv) * 1024) * 64;
    const unsigned short* vth = vbt + (((size_t)b * 6 + kv) * 64) * 1024;
    unsigned short* Pw = P_lds + w * 32 * LDP;

    f32x4 O[2][4];
#pragma unroll
    for (int i = 0; i < 2; ++i)
#pragma unroll
        for (int j = 0; j < 4; ++j) O[i][j] = (f32x4){0.f, 0.f, 0.f, 0.f};
    float m_r[2] = {-1e30f, -1e30f};
    float l_r[2] = {0.f, 0.f};

    for (int t = 0; t < 8; ++t) {
        const int kt0 = t * 128;
        f32x4 S[8][2];
#pragma unroll
        for (int mb = 0; mb < 8; ++mb) {
            S[mb][0] = (f32x4){0.f, 0.f, 0.f, 0.f};
            S[mb][1] = (f32x4){0.f, 0.f, 0.f, 0.f};
        }
        // S^T[key][q] += K-frag * Q-frag
#pragma unroll
        for (int ks = 0; ks < 2; ++ks) {
            bf16x8 bQ0 = *(const bf16x8*)(qh + (size_t)(c) * 64 + ks * 32 + g * 8);
            bf16x8 bQ1 = *(const bf16x8*)(qh + (size_t)(16 + c) * 64 + ks * 32 + g * 8);
#pragma unroll
            for (int mb = 0; mb < 8; ++mb) {
                bf16x8 aK = *(const bf16x8*)(kh + (size_t)(kt0 + mb * 16 + c) * 64 + ks * 32 + g * 8);
                S[mb][0] = MFMA16(aK, bQ0, S[mb][0]);
                S[mb][1] = MFMA16(aK, bQ1, S[mb][1]);
            }
        }
        // online softmax (per query col c, replicated across g after reduce)
#pragma unroll
        for (int qn = 0; qn < 2; ++qn) {
            float mt = -1e30f;
#pragma unroll
            for (int mb = 0; mb < 8; ++mb)
#pragma unroll
                for (int r = 0; r < 4; ++r) mt = fmaxf(mt, S[mb][qn][r]);
            mt = fmaxf(mt, __shfl_xor(mt, 16, 64));
            mt = fmaxf(mt, __shfl_xor(mt, 32, 64));
            float mnew = fmaxf(m_r[qn], mt);
            float alpha = __expf(m_r[qn] - mnew);
            float lt = 0.f;
#pragma unroll
            for (int mb = 0; mb < 8; ++mb) {
#pragma unroll
                for (int r = 0; r < 4; ++r) {
                    float p = __expf(S[mb][qn][r] - mnew);
                    S[mb][qn][r] = p;
                    lt += p;
                }
            }
            lt += __shfl_xor(lt, 16, 64);
            lt += __shfl_xor(lt, 32, 64);
            l_r[qn] = l_r[qn] * alpha + lt;
            m_r[qn] = mnew;
            if (g == 0) alpha_s[w][qn * 16 + c] = alpha;
            // P -> LDS bf16, row = query, col = key (pad LDP)
#pragma unroll
            for (int mb = 0; mb < 8; ++mb) {
                uint2 uu;
                uu.x = pack_bf16x2(S[mb][qn][0], S[mb][qn][1]);
                uu.y = pack_bf16x2(S[mb][qn][2], S[mb][qn][3]);
                *(uint2*)&Pw[(size_t)(qn * 16 + c) * LDP + mb * 16 + g * 4] = uu;
            }
        }
        // O = O*alpha + P·V
        f32x4 al0 = *(f32x4*)&alpha_s[w][g * 4];
        f32x4 al1 = *(f32x4*)&alpha_s[w][16 + g * 4];
#pragma unroll
        for (int nb = 0; nb < 4; ++nb)
#pragma unroll
            for (int r = 0; r < 4; ++r) {
                O[0][nb][r] *= al0[r];
                O[1][nb][r] *= al1[r];
            }
#pragma unroll
        for (int ks = 0; ks < 4; ++ks) {
            bf16x8 aP0 = *(const bf16x8*)&Pw[(size_t)(c) * LDP + ks * 32 + g * 8];
            bf16x8 aP1 = *(const bf16x8*)&Pw[(size_t)(16 + c) * LDP + ks * 32 + g * 8];
#pragma unroll
            for (int nb = 0; nb < 4; ++nb) {
                bf16x8 bV = *(const bf16x8*)(vth + (size_t)(nb * 16 + c) * 1024 + kt0 + ks * 32 + g * 8);
                O[0][nb] = MFMA16(aP0, bV, O[0][nb]);
                O[1][nb] = MFMA16(aP1, bV, O[1][nb]);
            }
        }
    }
    // epilogue: O /= l, write fp32 attb [b][q][768]
    if (g == 0) { l_s[w][c] = l_r[0]; l_s[w][16 + c] = l_r[1]; }
    f32x4 li0 = *(f32x4*)&l_s[w][g * 4];
    f32x4 li1 = *(f32x4*)&l_s[w][16 + g * 4];
    float inv0[4], inv1[4];
#pragma unroll
    for (int r = 0; r < 4; ++r) { inv0[r] = 1.f / li0[r]; inv1[r] = 1.f / li1[r]; }
    float* ob = attb + ((size_t)b * 1024 + qt0 + w * 32) * 768 + h * 64;
#pragma unroll
    for (int r = 0; r < 4; ++r) {
#pragma unroll
        for (int nb = 0; nb < 4; ++nb) {
            ob[(size_t)(g * 4 + r) * 768 + nb * 16 + c]      = O[0][nb][r] * inv0[r];
            ob[(size_t)(16 + g * 4 + r) * 768 + nb * 16 + c] = O[1][nb][r] * inv1[r];
        }
    }
}

// ---------------- per-(b,h) stats + noise subtraction ------------------------
__global__ __launch_bounds__(NTHREADS) void stats_norm_k(
    float* __restrict__ attb, const float* __restrict__ zb)
{
    int bh = blockIdx.x;
    int b = bh / 12, h = bh % 12;
    float* base = attb + ((size_t)b * 1024) * 768 + h * 64;
    float sum = 0.f, sumsq = 0.f;
    for (int f = threadIdx.x; f < 16384; f += NTHREADS) {
        int p = f >> 4, dq = (f & 15) * 4;
        float4 a = *(const float4*)(base + (size_t)p * 768 + dq);
        sum   += a.x + a.y + a.z + a.w;
        sumsq += a.x * a.x + a.y * a.y + a.z * a.z + a.w * a.w;
    }
    __shared__ float rbuf[8];
    sum = wave_sum64(sum); sumsq = wave_sum64(sumsq);
    int lane = threadIdx.x & 63, wv = threadIdx.x >> 6;
    if (lane == 0) { rbuf[wv] = sum; rbuf[4 + wv] = sumsq; }
    __syncthreads();
    sum   = rbuf[0] + rbuf[1] + rbuf[2] + rbuf[3];
    sumsq = rbuf[4] + rbuf[5] + rbuf[6] + rbuf[7];
    float mean = sum * (1.f / 65536.f);
    float var  = (sumsq - 65536.f * mean * mean) * (1.f / 65535.f);
    float sd   = sqrtf(fmaxf(var, 0.f));
    const float* zrow = zb + (size_t)h * 65536;
    for (int f = threadIdx.x; f < 16384; f += NTHREADS) {
        int p = f >> 4, dq = (f & 15) * 4;
        float4 a = *(const float4*)(base + (size_t)p * 768 + dq);
        float4 z = *(const float4*)(zrow + (size_t)f * 4);
        a.x -= z.x * sd + mean;
        a.y -= z.y * sd + mean;
        a.z -= z.z * sd + mean;
        a.w -= z.w * sd + mean;
        *(float4*)(base + (size_t)p * 768 + dq) = a;
    }
}

extern "C" void kernel_launch(void* const* d_in, const int* in_sizes, int n_in,
                              void* d_out, int out_size, void* d_ws, size_t ws_size,
                              hipStream_t stream) {
    const float* x  = (const float*)d_in[0];
    const float* Wq = (const float*)d_in[1];
    const float* Wk = (const float*)d_in[2];
    const float* Wv = (const float*)d_in[3];
    const float* Wp = (const float*)d_in[4];
    const float* bp = (const float*)d_in[5];
    float* out = (float*)d_out;

    float* ws    = (float*)d_ws;
    float* attb  = ws;                    // 8192*768 f
    float* zb    = attb + 6291456;        // 786432 f
    float* zpart = zb + 786432;           // 192 f
    unsigned short* qbh = (unsigned short*)(zpart + 192);  // 6291456 us
    unsigned short* kbh = qbh + 6291456;                   // 3145728 us
    unsigned short* vbt = kbh + 3145728;                   // 3145728 us

    z1_k<<<96, NTHREADS, 0, stream>>>(zb, zpart);
    z2_k<<<96, NTHREADS, 0, stream>>>(zb, zpart);
    qkv_gemm_k<<<dim3(12, 64), NTHREADS, 0, stream>>>(x, Wq, Wk, Wv, qbh, kbh, vbt);
    attn_mfma_k<<<dim3(8, 12, 8), NTHREADS, 0, stream>>>(qbh, kbh, vbt, attb);
    stats_norm_k<<<96, NTHREADS, 0, stream>>>(attb, zb);
    proj_gemm_k<<<dim3(6, 64), NTHREADS, 0, stream>>>(attb, Wp, bp, out);
}

// Round 4
// 320.968 us; speedup vs baseline: 6.8352x; 1.9898x over previous
//
#include <hip/hip_runtime.h>
#include <hip/hip_bf16.h>
#include <math.h>

// B=8, P=1024, DIM=768, H=12, KV=6, GS=2, HD=64
// R4: bf16-MFMA everywhere. qkv/proj = 128x128-tile MFMA GEMM with
// global_load_lds staging; attention = R3 flash kernel (bf16 attb out);
// stats/noise in bf16. Z field (Threefry partitionable) unchanged fp32.

#define NTHREADS 256

typedef __bf16 bf16x8 __attribute__((ext_vector_type(8)));
typedef float f32x4 __attribute__((ext_vector_type(4)));

#define MFMA16(a, b, c) __builtin_amdgcn_mfma_f32_16x16x32_bf16(a, b, c, 0, 0, 0)

__device__ __forceinline__ void gload16(const void* g, void* l) {
    __builtin_amdgcn_global_load_lds(
        (const __attribute__((address_space(1))) void*)g,
        (__attribute__((address_space(3))) void*)l, 16, 0, 0);
}

// ---------------- Threefry-2x32 partitionable, key=(0,42) --------------------
__device__ __forceinline__ unsigned rotl_u32(unsigned x, int r) {
    return (x << r) | (x >> (32 - r));
}
__device__ __forceinline__ void threefry_0_42(unsigned x0, unsigned x1,
                                              unsigned& o0, unsigned& o1) {
    const unsigned ks0 = 0u, ks1 = 42u, ks2 = 0u ^ 42u ^ 0x1BD11BDAu;
    x0 += ks0; x1 += ks1;
#define R4(a,b,c,d) \
    x0 += x1; x1 = rotl_u32(x1,a); x1 ^= x0; \
    x0 += x1; x1 = rotl_u32(x1,b); x1 ^= x0; \
    x0 += x1; x1 = rotl_u32(x1,c); x1 ^= x0; \
    x0 += x1; x1 = rotl_u32(x1,d); x1 ^= x0;
    R4(13,15,26,6)   x0 += ks1; x1 += ks2 + 1u;
    R4(17,29,16,24)  x0 += ks2; x1 += ks0 + 2u;
    R4(13,15,26,6)   x0 += ks0; x1 += ks1 + 3u;
    R4(17,29,16,24)  x0 += ks1; x1 += ks2 + 4u;
    R4(13,15,26,6)   x0 += ks2; x1 += ks0 + 5u;
#undef R4
    o0 = x0; o1 = x1;
}
__device__ __forceinline__ float tf_uniform(unsigned i) {
    unsigned o0, o1;
    threefry_0_42(0u, i, o0, o1);
    unsigned bits = o0 ^ o1;
    return __uint_as_float((bits >> 9) | 0x3f800000u) - 1.0f;
}

__device__ __forceinline__ float wave_sum64(float v) {
#pragma unroll
    for (int off = 32; off; off >>= 1) v += __shfl_xor(v, off, 64);
    return v;
}

__device__ __forceinline__ unsigned short bf16_rne(float x) {
    unsigned u = __float_as_uint(x);
    return (unsigned short)((u + 0x7fffu + ((u >> 16) & 1u)) >> 16);
}
__device__ __forceinline__ unsigned pack_bf16x2(float lo, float hi) {
    return (unsigned)bf16_rne(lo) | ((unsigned)bf16_rne(hi) << 16);
}
__device__ __forceinline__ float bfu(unsigned v) {
    return __uint_as_float(v << 16);
}

// ---------------- Z kernels --------------------------------------------------
__global__ __launch_bounds__(NTHREADS) void z1_k(float* __restrict__ zb,
                                                 float* __restrict__ zpart) {
    int bh = blockIdx.x;
    int row = bh >> 3, chunk = bh & 7;
    int g = row & 1;
    int j0 = chunk * 8192;
    float sum = 0.f, sumsq = 0.f;
    for (int t = threadIdx.x; t < 8192; t += NTHREADS) {
        int j = j0 + t;
        unsigned i = (unsigned)row * 65536u + (unsigned)j;
        float m = tf_uniform(i);
        if (j == g) m = 0.f;
        zb[i] = m;
        sum += m; sumsq += m * m;
    }
    __shared__ float rbuf[8];
    sum = wave_sum64(sum); sumsq = wave_sum64(sumsq);
    int lane = threadIdx.x & 63, wv = threadIdx.x >> 6;
    if (lane == 0) { rbuf[wv] = sum; rbuf[4 + wv] = sumsq; }
    __syncthreads();
    if (threadIdx.x == 0) {
        zpart[bh * 2]     = rbuf[0] + rbuf[1] + rbuf[2] + rbuf[3];
        zpart[bh * 2 + 1] = rbuf[4] + rbuf[5] + rbuf[6] + rbuf[7];
    }
}

__global__ __launch_bounds__(NTHREADS) void z2_k(float* __restrict__ zb,
                                                 const float* __restrict__ zpart) {
    int bh = blockIdx.x;
    int row = bh >> 3, chunk = bh & 7;
    float s = 0.f, s2 = 0.f;
    for (int c = 0; c < 8; ++c) {
        s  += zpart[(row * 8 + c) * 2];
        s2 += zpart[(row * 8 + c) * 2 + 1];
    }
    float mean = s * (1.f / 65536.f);
    float var  = (s2 - 65536.f * mean * mean) * (1.f / 65535.f);
    float sd   = sqrtf(fmaxf(var, 0.f));
    if (sd == 0.f) sd = 1.f;
    float rstd = 1.f / sd;
    int j0 = chunk * 8192;
    for (int t = threadIdx.x; t < 8192; t += NTHREADS) {
        unsigned i = (unsigned)row * 65536u + (unsigned)(j0 + t);
        zb[i] = (zb[i] - mean) * rstd;
    }
}

// ---------------- cast kernels -----------------------------------------------
// x fp32 -> bf16 flat (6291456 elems = 1572864 float4)
__global__ __launch_bounds__(NTHREADS) void cast_x_k(
    const float* __restrict__ x, unsigned short* __restrict__ xb)
{
    int i = blockIdx.x * NTHREADS + threadIdx.x;
    float4 v = ((const float4*)x)[i];
    uint2 u;
    u.x = pack_bf16x2(v.x, v.y);
    u.y = pack_bf16x2(v.z, v.w);
    *(uint2*)(xb + (size_t)i * 4) = u;
}

// W [K][N] fp32 -> Wt [N][K=768] bf16, 64x64 tiles. 432 blocks total.
__global__ __launch_bounds__(NTHREADS) void cast_w_k(
    const float* __restrict__ Wq, const float* __restrict__ Wk,
    const float* __restrict__ Wv, const float* __restrict__ Wp,
    unsigned short* __restrict__ wqt, unsigned short* __restrict__ wkt,
    unsigned short* __restrict__ wvt, unsigned short* __restrict__ wpt)
{
    int id = blockIdx.x;
    const float* W; unsigned short* Wt; int N;
    if (id < 144)      { W = Wq; Wt = wqt; N = 768; }
    else if (id < 216) { W = Wk; Wt = wkt; N = 384; id -= 144; }
    else if (id < 288) { W = Wv; Wt = wvt; N = 384; id -= 216; }
    else               { W = Wp; Wt = wpt; N = 768; id -= 288; }
    int ntn = N >> 6;
    int kt = id / ntn, nt = id % ntn;
    int k0 = kt * 64, n0 = nt * 64;
    int t = threadIdx.x;
    int tn = t & 63, tk = t >> 6;
    float r[16];
#pragma unroll
    for (int j = 0; j < 16; ++j)
        r[j] = W[(size_t)(k0 + tk * 16 + j) * N + n0 + tn];
    uint4 u0, u1;
    u0.x = pack_bf16x2(r[0], r[1]);  u0.y = pack_bf16x2(r[2], r[3]);
    u0.z = pack_bf16x2(r[4], r[5]);  u0.w = pack_bf16x2(r[6], r[7]);
    u1.x = pack_bf16x2(r[8], r[9]);  u1.y = pack_bf16x2(r[10], r[11]);
    u1.z = pack_bf16x2(r[12], r[13]); u1.w = pack_bf16x2(r[14], r[15]);
    unsigned short* dst = Wt + (size_t)(n0 + tn) * 768 + k0 + tk * 16;
    *(uint4*)dst = u0;
    *(uint4*)(dst + 8) = u1;
}

// ---------------- bf16 MFMA GEMM core: 128x128 tile, BK=32 -------------------
// A[M][K] bf16 row-major, Bt[N][K] bf16 row-major. 256 thr = 4 waves; wave w
// computes 64x64 at (m0=(w&1)*64, n0=(w>>1)*64). LDS tiles staged via
// global_load_lds w=16 into [chunk16][kgroup][row16][8] layout (contiguous in
// lane order; fragment ds_read_b128 hits a contiguous 256B run -> no conflicts)
__device__ __forceinline__ void mfma_tile_compute(
    const unsigned short* __restrict__ A, const unsigned short* __restrict__ Bt,
    int lda, int ldb, int row0, int col0, int K,
    unsigned short* As, unsigned short* Bs, f32x4 acc[4][4])
{
    const int tid = threadIdx.x;
    const int w = tid >> 6, lane = tid & 63;
    const int c = lane & 15, g = lane >> 4;
    const int m0 = (w & 1) * 64, n0 = (w >> 1) * 64;

#pragma unroll
    for (int mi = 0; mi < 4; ++mi)
#pragma unroll
        for (int ni = 0; ni < 4; ++ni) acc[mi][ni] = (f32x4){0.f, 0.f, 0.f, 0.f};

    const unsigned short* Ag0 = A + (size_t)(row0 + w * 16 + c) * lda + g * 8;
    const unsigned short* Ag1 = A + (size_t)(row0 + (w + 4) * 16 + c) * lda + g * 8;
    const unsigned short* Bg0 = Bt + (size_t)(col0 + w * 16 + c) * ldb + g * 8;
    const unsigned short* Bg1 = Bt + (size_t)(col0 + (w + 4) * 16 + c) * ldb + g * 8;
    unsigned short* Al0 = As + w * 512 + lane * 8;
    unsigned short* Al1 = As + (w + 4) * 512 + lane * 8;
    unsigned short* Bl0 = Bs + w * 512 + lane * 8;
    unsigned short* Bl1 = Bs + (w + 4) * 512 + lane * 8;

    for (int k0 = 0; k0 < K; k0 += 32) {
        __syncthreads();
        gload16(Ag0 + k0, Al0);
        gload16(Ag1 + k0, Al1);
        gload16(Bg0 + k0, Bl0);
        gload16(Bg1 + k0, Bl1);
        __syncthreads();
        bf16x8 aA[4], bB[4];
#pragma unroll
        for (int mi = 0; mi < 4; ++mi)
            aA[mi] = *(const bf16x8*)&As[(size_t)((m0 >> 4) + mi) * 512 + g * 128 + c * 8];
#pragma unroll
        for (int ni = 0; ni < 4; ++ni)
            bB[ni] = *(const bf16x8*)&Bs[(size_t)((n0 >> 4) + ni) * 512 + g * 128 + c * 8];
#pragma unroll
        for (int mi = 0; mi < 4; ++mi)
#pragma unroll
            for (int ni = 0; ni < 4; ++ni)
                acc[mi][ni] = MFMA16(aA[mi], bB[ni], acc[mi][ni]);
    }
}

// qkv: A=xb, Bt per column block; epilogue into head-separated bf16 buffers.
// grid.x: 0..5 q-cols, 6..8 k-cols, 9..11 v-cols; grid.y: 64 m-blocks
__global__ __launch_bounds__(NTHREADS) void qkv_mfma_k(
    const unsigned short* __restrict__ xb, const unsigned short* __restrict__ wqt,
    const unsigned short* __restrict__ wkt, const unsigned short* __restrict__ wvt,
    unsigned short* __restrict__ qbh, unsigned short* __restrict__ kbh,
    unsigned short* __restrict__ vbt)
{
    __shared__ unsigned short As[4096];
    __shared__ unsigned short Bs[4096];
    int nb = blockIdx.x;
    int row0 = blockIdx.y * 128;
    const unsigned short* Bt; int col0; int mode;
    if (nb < 6)      { Bt = wqt; col0 = nb * 128;       mode = 0; }
    else if (nb < 9) { Bt = wkt; col0 = (nb - 6) * 128; mode = 1; }
    else             { Bt = wvt; col0 = (nb - 9) * 128; mode = 2; }

    f32x4 acc[4][4];
    mfma_tile_compute(xb, Bt, 768, 768, row0, col0, 768, As, Bs, acc);

    const int tid = threadIdx.x;
    const int w = tid >> 6, lane = tid & 63;
    const int c = lane & 15, g = lane >> 4;
    const int m0 = (w & 1) * 64, n0 = (w >> 1) * 64;
    int b = row0 >> 10;
    int pbase = (row0 & 1023) + m0;

#pragma unroll
    for (int mi = 0; mi < 4; ++mi) {
#pragma unroll
        for (int ni = 0; ni < 4; ++ni) {
            int colg = col0 + n0 + ni * 16 + c;
            if (mode == 2) {
                int kv = colg >> 6, d = colg & 63;
                int p = pbase + mi * 16 + g * 4;
                ushort4 u;
                u.x = bf16_rne(acc[mi][ni][0]);
                u.y = bf16_rne(acc[mi][ni][1]);
                u.z = bf16_rne(acc[mi][ni][2]);
                u.w = bf16_rne(acc[mi][ni][3]);
                *(ushort4*)&vbt[(((size_t)b * 6 + kv) * 64 + d) * 1024 + p] = u;
            } else if (mode == 0) {
                int h = colg >> 6, d = colg & 63;
#pragma unroll
                for (int r = 0; r < 4; ++r) {
                    int p = pbase + mi * 16 + g * 4 + r;
                    qbh[(((size_t)b * 12 + h) * 1024 + p) * 64 + d] =
                        bf16_rne(acc[mi][ni][r] * 0.125f);
                }
            } else {
                int kv = colg >> 6, d = colg & 63;
#pragma unroll
                for (int r = 0; r < 4; ++r) {
                    int p = pbase + mi * 16 + g * 4 + r;
                    kbh[(((size_t)b * 6 + kv) * 1024 + p) * 64 + d] =
                        bf16_rne(acc[mi][ni][r]);
                }
            }
        }
    }
}

// proj: A=attb (bf16), Bt=wpt; fp32 out + bias
__global__ __launch_bounds__(NTHREADS) void proj_mfma_k(
    const unsigned short* __restrict__ attb, const unsigned short* __restrict__ wpt,
    const float* __restrict__ bp, float* __restrict__ out)
{
    __shared__ unsigned short As[4096];
    __shared__ unsigned short Bs[4096];
    int row0 = blockIdx.y * 128, col0 = blockIdx.x * 128;
    f32x4 acc[4][4];
    mfma_tile_compute(attb, wpt, 768, 768, row0, col0, 768, As, Bs, acc);

    const int tid = threadIdx.x;
    const int w = tid >> 6, lane = tid & 63;
    const int c = lane & 15, g = lane >> 4;
    const int m0 = (w & 1) * 64, n0 = (w >> 1) * 64;
#pragma unroll
    for (int ni = 0; ni < 4; ++ni) {
        int colg = col0 + n0 + ni * 16 + c;
        float bias = bp[colg];
#pragma unroll
        for (int mi = 0; mi < 4; ++mi) {
#pragma unroll
            for (int r = 0; r < 4; ++r) {
                int rowg = row0 + m0 + mi * 16 + g * 4 + r;
                out[(size_t)rowg * 768 + colg] = acc[mi][ni][r] + bias;
            }
        }
    }
}

// ---------------- bf16 MFMA flash attention (R3, bf16 attb out) --------------
#define LDP 136
__global__ __launch_bounds__(NTHREADS) void attn_mfma_k(
    const unsigned short* __restrict__ qbh, const unsigned short* __restrict__ kbh,
    const unsigned short* __restrict__ vbt, unsigned short* __restrict__ attb)
{
    __shared__ unsigned short P_lds[4 * 32 * LDP];
    __shared__ float alpha_s[4][32];
    __shared__ float l_s[4][32];

    const int qt0 = blockIdx.x * 128;
    const int h = blockIdx.y, b = blockIdx.z, kv = h >> 1;
    const int tid = threadIdx.x;
    const int w = tid >> 6, lane = tid & 63;
    const int c = lane & 15, g = lane >> 4;

    const unsigned short* qh = qbh + (((size_t)b * 12 + h) * 1024 + qt0 + w * 32) * 64;
    const unsigned short* kh = kbh + (((size_t)b * 6 + kv) * 1024) * 64;
    const unsigned short* vth = vbt + (((size_t)b * 6 + kv) * 64) * 1024;
    unsigned short* Pw = P_lds + w * 32 * LDP;

    f32x4 O[2][4];
#pragma unroll
    for (int i = 0; i < 2; ++i)
#pragma unroll
        for (int j = 0; j < 4; ++j) O[i][j] = (f32x4){0.f, 0.f, 0.f, 0.f};
    float m_r[2] = {-1e30f, -1e30f};
    float l_r[2] = {0.f, 0.f};

    for (int t = 0; t < 8; ++t) {
        const int kt0 = t * 128;
        f32x4 S[8][2];
#pragma unroll
        for (int mb = 0; mb < 8; ++mb) {
            S[mb][0] = (f32x4){0.f, 0.f, 0.f, 0.f};
            S[mb][1] = (f32x4){0.f, 0.f, 0.f, 0.f};
        }
#pragma unroll
        for (int ks = 0; ks < 2; ++ks) {
            bf16x8 bQ0 = *(const bf16x8*)(qh + (size_t)(c) * 64 + ks * 32 + g * 8);
            bf16x8 bQ1 = *(const bf16x8*)(qh + (size_t)(16 + c) * 64 + ks * 32 + g * 8);
#pragma unroll
            for (int mb = 0; mb < 8; ++mb) {
                bf16x8 aK = *(const bf16x8*)(kh + (size_t)(kt0 + mb * 16 + c) * 64 + ks * 32 + g * 8);
                S[mb][0] = MFMA16(aK, bQ0, S[mb][0]);
                S[mb][1] = MFMA16(aK, bQ1, S[mb][1]);
            }
        }
#pragma unroll
        for (int qn = 0; qn < 2; ++qn) {
            float mt = -1e30f;
#pragma unroll
            for (int mb = 0; mb < 8; ++mb)
#pragma unroll
                for (int r = 0; r < 4; ++r) mt = fmaxf(mt, S[mb][qn][r]);
            mt = fmaxf(mt, __shfl_xor(mt, 16, 64));
            mt = fmaxf(mt, __shfl_xor(mt, 32, 64));
            float mnew = fmaxf(m_r[qn], mt);
            float alpha = __expf(m_r[qn] - mnew);
            float lt = 0.f;
#pragma unroll
            for (int mb = 0; mb < 8; ++mb) {
#pragma unroll
                for (int r = 0; r < 4; ++r) {
                    float p = __expf(S[mb][qn][r] - mnew);
                    S[mb][qn][r] = p;
                    lt += p;
                }
            }
            lt += __shfl_xor(lt, 16, 64);
            lt += __shfl_xor(lt, 32, 64);
            l_r[qn] = l_r[qn] * alpha + lt;
            m_r[qn] = mnew;
            if (g == 0) alpha_s[w][qn * 16 + c] = alpha;
#pragma unroll
            for (int mb = 0; mb < 8; ++mb) {
                uint2 uu;
                uu.x = pack_bf16x2(S[mb][qn][0], S[mb][qn][1]);
                uu.y = pack_bf16x2(S[mb][qn][2], S[mb][qn][3]);
                *(uint2*)&Pw[(size_t)(qn * 16 + c) * LDP + mb * 16 + g * 4] = uu;
            }
        }
        f32x4 al0 = *(f32x4*)&alpha_s[w][g * 4];
        f32x4 al1 = *(f32x4*)&alpha_s[w][16 + g * 4];
#pragma unroll
        for (int nb = 0; nb < 4; ++nb)
#pragma unroll
            for (int r = 0; r < 4; ++r) {
                O[0][nb][r] *= al0[r];
                O[1][nb][r] *= al1[r];
            }
#pragma unroll
        for (int ks = 0; ks < 4; ++ks) {
            bf16x8 aP0 = *(const bf16x8*)&Pw[(size_t)(c) * LDP + ks * 32 + g * 8];
            bf16x8 aP1 = *(const bf16x8*)&Pw[(size_t)(16 + c) * LDP + ks * 32 + g * 8];
#pragma unroll
            for (int nb = 0; nb < 4; ++nb) {
                bf16x8 bV = *(const bf16x8*)(vth + (size_t)(nb * 16 + c) * 1024 + kt0 + ks * 32 + g * 8);
                O[0][nb] = MFMA16(aP0, bV, O[0][nb]);
                O[1][nb] = MFMA16(aP1, bV, O[1][nb]);
            }
        }
    }
    if (g == 0) { l_s[w][c] = l_r[0]; l_s[w][16 + c] = l_r[1]; }
    f32x4 li0 = *(f32x4*)&l_s[w][g * 4];
    f32x4 li1 = *(f32x4*)&l_s[w][16 + g * 4];
    float inv0[4], inv1[4];
#pragma unroll
    for (int r = 0; r < 4; ++r) { inv0[r] = 1.f / li0[r]; inv1[r] = 1.f / li1[r]; }
    unsigned short* ob = attb + ((size_t)b * 1024 + qt0 + w * 32) * 768 + h * 64;
#pragma unroll
    for (int r = 0; r < 4; ++r) {
#pragma unroll
        for (int nb = 0; nb < 4; ++nb) {
            ob[(size_t)(g * 4 + r) * 768 + nb * 16 + c]      = bf16_rne(O[0][nb][r] * inv0[r]);
            ob[(size_t)(16 + g * 4 + r) * 768 + nb * 16 + c] = bf16_rne(O[1][nb][r] * inv1[r]);
        }
    }
}

// ---------------- per-(b,h) stats + noise subtraction (bf16 in/out) ----------
__global__ __launch_bounds__(NTHREADS) void stats_norm_k(
    unsigned short* __restrict__ attb, const float* __restrict__ zb)
{
    int bh = blockIdx.x;
    int b = bh / 12, h = bh % 12;
    unsigned short* base = attb + ((size_t)b * 1024) * 768 + h * 64;
    float sum = 0.f, sumsq = 0.f;
    for (int f = threadIdx.x; f < 8192; f += NTHREADS) {   // 8-elem groups
        int p = f >> 3, dq = (f & 7) * 8;
        uint4 u = *(const uint4*)(base + (size_t)p * 768 + dq);
        float v0 = bfu(u.x), v1 = bfu(u.x >> 16);
        float v2 = bfu(u.y), v3 = bfu(u.y >> 16);
        float v4 = bfu(u.z), v5 = bfu(u.z >> 16);
        float v6 = bfu(u.w), v7 = bfu(u.w >> 16);
        sum   += (v0 + v1) + (v2 + v3) + (v4 + v5) + (v6 + v7);
        sumsq += (v0*v0 + v1*v1) + (v2*v2 + v3*v3) + (v4*v4 + v5*v5) + (v6*v6 + v7*v7);
    }
    __shared__ float rbuf[8];
    sum = wave_sum64(sum); sumsq = wave_sum64(sumsq);
    int lane = threadIdx.x & 63, wv = threadIdx.x >> 6;
    if (lane == 0) { rbuf[wv] = sum; rbuf[4 + wv] = sumsq; }
    __syncthreads();
    sum   = rbuf[0] + rbuf[1] + rbuf[2] + rbuf[3];
    sumsq = rbuf[4] + rbuf[5] + rbuf[6] + rbuf[7];
    float mean = sum * (1.f / 65536.f);
    float var  = (sumsq - 65536.f * mean * mean) * (1.f / 65535.f);
    float sd   = sqrtf(fmaxf(var, 0.f));
    const float* zrow = zb + (size_t)h * 65536;
    for (int f = threadIdx.x; f < 8192; f += NTHREADS) {
        int p = f >> 3, dq = (f & 7) * 8;
        unsigned short* ptr = base + (size_t)p * 768 + dq;
        uint4 u = *(const uint4*)ptr;
        const float* zp = zrow + (size_t)f * 8;
        float4 z0 = *(const float4*)zp;
        float4 z1 = *(const float4*)(zp + 4);
        float v0 = bfu(u.x)       - (z0.x * sd + mean);
        float v1 = bfu(u.x >> 16) - (z0.y * sd + mean);
        float v2 = bfu(u.y)       - (z0.z * sd + mean);
        float v3 = bfu(u.y >> 16) - (z0.w * sd + mean);
        float v4 = bfu(u.z)       - (z1.x * sd + mean);
        float v5 = bfu(u.z >> 16) - (z1.y * sd + mean);
        float v6 = bfu(u.w)       - (z1.z * sd + mean);
        float v7 = bfu(u.w >> 16) - (z1.w * sd + mean);
        uint4 o;
        o.x = pack_bf16x2(v0, v1);
        o.y = pack_bf16x2(v2, v3);
        o.z = pack_bf16x2(v4, v5);
        o.w = pack_bf16x2(v6, v7);
        *(uint4*)ptr = o;
    }
}

extern "C" void kernel_launch(void* const* d_in, const int* in_sizes, int n_in,
                              void* d_out, int out_size, void* d_ws, size_t ws_size,
                              hipStream_t stream) {
    const float* x  = (const float*)d_in[0];
    const float* Wq = (const float*)d_in[1];
    const float* Wk = (const float*)d_in[2];
    const float* Wv = (const float*)d_in[3];
    const float* Wp = (const float*)d_in[4];
    const float* bp = (const float*)d_in[5];
    float* out = (float*)d_out;

    float* ws    = (float*)d_ws;
    float* zb    = ws;                    // 786432 f
    float* zpart = zb + 786432;           // 192 f
    unsigned short* xb   = (unsigned short*)(zpart + 192);  // 6291456
    unsigned short* wqt  = xb + 6291456;   // 589824
    unsigned short* wkt  = wqt + 589824;   // 294912
    unsigned short* wvt  = wkt + 294912;   // 294912
    unsigned short* wpt  = wvt + 294912;   // 589824
    unsigned short* qbh  = wpt + 589824;   // 6291456
    unsigned short* kbh  = qbh + 6291456;  // 3145728
    unsigned short* vbt  = kbh + 3145728;  // 3145728
    unsigned short* attb = vbt + 3145728;  // 6291456

    z1_k<<<96, NTHREADS, 0, stream>>>(zb, zpart);
    z2_k<<<96, NTHREADS, 0, stream>>>(zb, zpart);
    cast_x_k<<<6144, NTHREADS, 0, stream>>>(x, xb);
    cast_w_k<<<432, NTHREADS, 0, stream>>>(Wq, Wk, Wv, Wp, wqt, wkt, wvt, wpt);
    qkv_mfma_k<<<dim3(12, 64), NTHREADS, 0, stream>>>(xb, wqt, wkt, wvt, qbh, kbh, vbt);
    attn_mfma_k<<<dim3(8, 12, 8), NTHREADS, 0, stream>>>(qbh, kbh, vbt, attb);
    stats_norm_k<<<96, NTHREADS, 0, stream>>>(attb, zb);
    proj_mfma_k<<<dim3(6, 64), NTHREADS, 0, stream>>>(attb, wpt, bp, out);
}

// Round 5
// 269.900 us; speedup vs baseline: 8.1285x; 1.1892x over previous
//
#include <hip/hip_runtime.h>
#include <hip/hip_bf16.h>
#include <math.h>

// B=8, P=1024, DIM=768, H=12, KV=6, GS=2, HD=64
// R5: MFMA-operand-native global layouts for K/V (kb2/vb2 tiled) so flash-attn
// fragment loads are fully coalesced; q/k/proj GEMMs run transposed so their
// epilogues emit wide contiguous stores.

#define NTHREADS 256

typedef __bf16 bf16x8 __attribute__((ext_vector_type(8)));
typedef float f32x4 __attribute__((ext_vector_type(4)));

#define MFMA16(a, b, c) __builtin_amdgcn_mfma_f32_16x16x32_bf16(a, b, c, 0, 0, 0)

__device__ __forceinline__ void gload16(const void* g, void* l) {
    __builtin_amdgcn_global_load_lds(
        (const __attribute__((address_space(1))) void*)g,
        (__attribute__((address_space(3))) void*)l, 16, 0, 0);
}

// ---------------- Threefry-2x32 partitionable, key=(0,42) --------------------
__device__ __forceinline__ unsigned rotl_u32(unsigned x, int r) {
    return (x << r) | (x >> (32 - r));
}
__device__ __forceinline__ void threefry_0_42(unsigned x0, unsigned x1,
                                              unsigned& o0, unsigned& o1) {
    const unsigned ks0 = 0u, ks1 = 42u, ks2 = 0u ^ 42u ^ 0x1BD11BDAu;
    x0 += ks0; x1 += ks1;
#define R4(a,b,c,d) \
    x0 += x1; x1 = rotl_u32(x1,a); x1 ^= x0; \
    x0 += x1; x1 = rotl_u32(x1,b); x1 ^= x0; \
    x0 += x1; x1 = rotl_u32(x1,c); x1 ^= x0; \
    x0 += x1; x1 = rotl_u32(x1,d); x1 ^= x0;
    R4(13,15,26,6)   x0 += ks1; x1 += ks2 + 1u;
    R4(17,29,16,24)  x0 += ks2; x1 += ks0 + 2u;
    R4(13,15,26,6)   x0 += ks0; x1 += ks1 + 3u;
    R4(17,29,16,24)  x0 += ks1; x1 += ks2 + 4u;
    R4(13,15,26,6)   x0 += ks2; x1 += ks0 + 5u;
#undef R4
    o0 = x0; o1 = x1;
}
__device__ __forceinline__ float tf_uniform(unsigned i) {
    unsigned o0, o1;
    threefry_0_42(0u, i, o0, o1);
    unsigned bits = o0 ^ o1;
    return __uint_as_float((bits >> 9) | 0x3f800000u) - 1.0f;
}

__device__ __forceinline__ float wave_sum64(float v) {
#pragma unroll
    for (int off = 32; off; off >>= 1) v += __shfl_xor(v, off, 64);
    return v;
}

__device__ __forceinline__ unsigned short bf16_rne(float x) {
    unsigned u = __float_as_uint(x);
    return (unsigned short)((u + 0x7fffu + ((u >> 16) & 1u)) >> 16);
}
__device__ __forceinline__ unsigned pack_bf16x2(float lo, float hi) {
    return (unsigned)bf16_rne(lo) | ((unsigned)bf16_rne(hi) << 16);
}
__device__ __forceinline__ float bfu(unsigned v) {
    return __uint_as_float(v << 16);
}

// ---------------- Z kernels --------------------------------------------------
__global__ __launch_bounds__(NTHREADS) void z1_k(float* __restrict__ zb,
                                                 float* __restrict__ zpart) {
    int bh = blockIdx.x;
    int row = bh >> 3, chunk = bh & 7;
    int g = row & 1;
    int j0 = chunk * 8192;
    float sum = 0.f, sumsq = 0.f;
    for (int t = threadIdx.x; t < 8192; t += NTHREADS) {
        int j = j0 + t;
        unsigned i = (unsigned)row * 65536u + (unsigned)j;
        float m = tf_uniform(i);
        if (j == g) m = 0.f;
        zb[i] = m;
        sum += m; sumsq += m * m;
    }
    __shared__ float rbuf[8];
    sum = wave_sum64(sum); sumsq = wave_sum64(sumsq);
    int lane = threadIdx.x & 63, wv = threadIdx.x >> 6;
    if (lane == 0) { rbuf[wv] = sum; rbuf[4 + wv] = sumsq; }
    __syncthreads();
    if (threadIdx.x == 0) {
        zpart[bh * 2]     = rbuf[0] + rbuf[1] + rbuf[2] + rbuf[3];
        zpart[bh * 2 + 1] = rbuf[4] + rbuf[5] + rbuf[6] + rbuf[7];
    }
}

__global__ __launch_bounds__(NTHREADS) void z2_k(float* __restrict__ zb,
                                                 const float* __restrict__ zpart) {
    int bh = blockIdx.x;
    int row = bh >> 3, chunk = bh & 7;
    float s = 0.f, s2 = 0.f;
    for (int c = 0; c < 8; ++c) {
        s  += zpart[(row * 8 + c) * 2];
        s2 += zpart[(row * 8 + c) * 2 + 1];
    }
    float mean = s * (1.f / 65536.f);
    float var  = (s2 - 65536.f * mean * mean) * (1.f / 65535.f);
    float sd   = sqrtf(fmaxf(var, 0.f));
    if (sd == 0.f) sd = 1.f;
    float rstd = 1.f / sd;
    int j0 = chunk * 8192;
    for (int t = threadIdx.x; t < 8192; t += NTHREADS) {
        unsigned i = (unsigned)row * 65536u + (unsigned)(j0 + t);
        zb[i] = (zb[i] - mean) * rstd;
    }
}

// ---------------- cast kernels -----------------------------------------------
__global__ __launch_bounds__(NTHREADS) void cast_x_k(
    const float* __restrict__ x, unsigned short* __restrict__ xb)
{
    int i = blockIdx.x * NTHREADS + threadIdx.x;
    float4 v = ((const float4*)x)[i];
    uint2 u;
    u.x = pack_bf16x2(v.x, v.y);
    u.y = pack_bf16x2(v.z, v.w);
    *(uint2*)(xb + (size_t)i * 4) = u;
}

// W [K][N] fp32 -> Wt [N][K=768] bf16, 64x64 tiles. 432 blocks.
__global__ __launch_bounds__(NTHREADS) void cast_w_k(
    const float* __restrict__ Wq, const float* __restrict__ Wk,
    const float* __restrict__ Wv, const float* __restrict__ Wp,
    unsigned short* __restrict__ wqt, unsigned short* __restrict__ wkt,
    unsigned short* __restrict__ wvt, unsigned short* __restrict__ wpt)
{
    int id = blockIdx.x;
    const float* W; unsigned short* Wt; int N;
    if (id < 144)      { W = Wq; Wt = wqt; N = 768; }
    else if (id < 216) { W = Wk; Wt = wkt; N = 384; id -= 144; }
    else if (id < 288) { W = Wv; Wt = wvt; N = 384; id -= 216; }
    else               { W = Wp; Wt = wpt; N = 768; id -= 288; }
    int ntn = N >> 6;
    int kt = id / ntn, nt = id % ntn;
    int k0 = kt * 64, n0 = nt * 64;
    int t = threadIdx.x;
    int tn = t & 63, tk = t >> 6;
    float r[16];
#pragma unroll
    for (int j = 0; j < 16; ++j)
        r[j] = W[(size_t)(k0 + tk * 16 + j) * N + n0 + tn];
    uint4 u0, u1;
    u0.x = pack_bf16x2(r[0], r[1]);  u0.y = pack_bf16x2(r[2], r[3]);
    u0.z = pack_bf16x2(r[4], r[5]);  u0.w = pack_bf16x2(r[6], r[7]);
    u1.x = pack_bf16x2(r[8], r[9]);  u1.y = pack_bf16x2(r[10], r[11]);
    u1.z = pack_bf16x2(r[12], r[13]); u1.w = pack_bf16x2(r[14], r[15]);
    unsigned short* dst = Wt + (size_t)(n0 + tn) * 768 + k0 + tk * 16;
    *(uint4*)dst = u0;
    *(uint4*)(dst + 8) = u1;
}

// ---------------- bf16 MFMA GEMM core: 128x128 tile, BK=32 -------------------
__device__ __forceinline__ void mfma_tile_compute(
    const unsigned short* __restrict__ A, const unsigned short* __restrict__ Bt,
    int row0, int col0,
    unsigned short* As, unsigned short* Bs, f32x4 acc[4][4])
{
    const int tid = threadIdx.x;
    const int w = tid >> 6, lane = tid & 63;
    const int c = lane & 15, g = lane >> 4;
    const int m0 = (w & 1) * 64, n0 = (w >> 1) * 64;

#pragma unroll
    for (int mi = 0; mi < 4; ++mi)
#pragma unroll
        for (int ni = 0; ni < 4; ++ni) acc[mi][ni] = (f32x4){0.f, 0.f, 0.f, 0.f};

    const unsigned short* Ag0 = A + (size_t)(row0 + w * 16 + c) * 768 + g * 8;
    const unsigned short* Ag1 = A + (size_t)(row0 + (w + 4) * 16 + c) * 768 + g * 8;
    const unsigned short* Bg0 = Bt + (size_t)(col0 + w * 16 + c) * 768 + g * 8;
    const unsigned short* Bg1 = Bt + (size_t)(col0 + (w + 4) * 16 + c) * 768 + g * 8;
    unsigned short* Al0 = As + w * 512 + lane * 8;
    unsigned short* Al1 = As + (w + 4) * 512 + lane * 8;
    unsigned short* Bl0 = Bs + w * 512 + lane * 8;
    unsigned short* Bl1 = Bs + (w + 4) * 512 + lane * 8;

    for (int k0 = 0; k0 < 768; k0 += 32) {
        __syncthreads();
        gload16(Ag0 + k0, Al0);
        gload16(Ag1 + k0, Al1);
        gload16(Bg0 + k0, Bl0);
        gload16(Bg1 + k0, Bl1);
        __syncthreads();
        bf16x8 aA[4], bB[4];
#pragma unroll
        for (int mi = 0; mi < 4; ++mi)
            aA[mi] = *(const bf16x8*)&As[(size_t)((m0 >> 4) + mi) * 512 + g * 128 + c * 8];
#pragma unroll
        for (int ni = 0; ni < 4; ++ni)
            bB[ni] = *(const bf16x8*)&Bs[(size_t)((n0 >> 4) + ni) * 512 + g * 128 + c * 8];
#pragma unroll
        for (int mi = 0; mi < 4; ++mi)
#pragma unroll
            for (int ni = 0; ni < 4; ++ni)
                acc[mi][ni] = MFMA16(aA[mi], bB[ni], acc[mi][ni]);
    }
}

// qkv: q,k transposed orientation (rows=out-channel, cols=p); v normal.
// grid.x: 0..5 q row-tiles, 6..8 k row-tiles, 9..11 v col-tiles; grid.y: p/128
__global__ __launch_bounds__(NTHREADS) void qkv_mfma_k(
    const unsigned short* __restrict__ xb, const unsigned short* __restrict__ wqt,
    const unsigned short* __restrict__ wkt, const unsigned short* __restrict__ wvt,
    unsigned short* __restrict__ qbh, unsigned short* __restrict__ kb2,
    unsigned short* __restrict__ vb2)
{
    __shared__ unsigned short As[4096];
    __shared__ unsigned short Bs[4096];
    int nb = blockIdx.x;
    int y0 = blockIdx.y * 128;
    f32x4 acc[4][4];

    const int tid = threadIdx.x;
    const int w = tid >> 6, lane = tid & 63;
    const int c = lane & 15, g = lane >> 4;
    const int m0 = (w & 1) * 64, n0 = (w >> 1) * 64;

    if (nb < 9) {
        // transposed: A = W^T rows (out-channels), B = x rows (p)
        int row0 = (nb < 6) ? nb * 128 : (nb - 6) * 128;
        const unsigned short* Wt = (nb < 6) ? wqt : wkt;
        mfma_tile_compute(Wt, xb, row0, y0, As, Bs, acc);
        float scale = (nb < 6) ? 0.125f : 1.0f;
#pragma unroll
        for (int mi = 0; mi < 4; ++mi) {
            int ocol = row0 + m0 + mi * 16 + g * 4;   // +r
#pragma unroll
            for (int ni = 0; ni < 4; ++ni) {
                int pglob = y0 + n0 + ni * 16 + c;
                int b = pglob >> 10, pin = pglob & 1023;
                ushort4 u;
                u.x = bf16_rne(acc[mi][ni][0] * scale);
                u.y = bf16_rne(acc[mi][ni][1] * scale);
                u.z = bf16_rne(acc[mi][ni][2] * scale);
                u.w = bf16_rne(acc[mi][ni][3] * scale);
                if (nb < 6) {
                    int h = ocol >> 6, d0 = ocol & 63;
                    *(ushort4*)&qbh[(((size_t)b * 12 + h) * 1024 + pin) * 64 + d0] = u;
                } else {
                    int kv = ocol >> 6, d0 = ocol & 63;
                    int kt = pin >> 7, key = pin & 127;
                    *(ushort4*)&kb2[((((size_t)(b * 6 + kv) * 8 + kt) * 8 + (d0 >> 3)) * 128
                                     + key) * 8 + (d0 & 7)] = u;
                }
            }
        }
    } else {
        // normal: A = x rows (p), B = Wv^T rows (v-channels)
        int col0 = (nb - 9) * 128;
        mfma_tile_compute(xb, wvt, y0, col0, As, Bs, acc);
#pragma unroll
        for (int mi = 0; mi < 4; ++mi) {
            int pglob = y0 + m0 + mi * 16 + g * 4;    // +r
            int b = pglob >> 10, pin = pglob & 1023;
            int kt = pin >> 7, pg = (pin & 127) >> 3, p8 = pin & 7;
#pragma unroll
            for (int ni = 0; ni < 4; ++ni) {
                int vcol = col0 + n0 + ni * 16 + c;
                int kv = vcol >> 6, d = vcol & 63;
                ushort4 u;
                u.x = bf16_rne(acc[mi][ni][0]);
                u.y = bf16_rne(acc[mi][ni][1]);
                u.z = bf16_rne(acc[mi][ni][2]);
                u.w = bf16_rne(acc[mi][ni][3]);
                *(ushort4*)&vb2[((((size_t)(b * 6 + kv) * 8 + kt) * 16 + pg) * 64 + d) * 8 + p8] = u;
            }
        }
    }
}

// proj transposed: rows = out-cols, cols = p -> float4 stores filling lines
__global__ __launch_bounds__(NTHREADS) void proj_mfma_k(
    const unsigned short* __restrict__ attb, const unsigned short* __restrict__ wpt,
    const float* __restrict__ bp, float* __restrict__ out)
{
    __shared__ unsigned short As[4096];
    __shared__ unsigned short Bs[4096];
    int row0 = blockIdx.x * 128, col0 = blockIdx.y * 128;
    f32x4 acc[4][4];
    mfma_tile_compute(wpt, attb, row0, col0, As, Bs, acc);

    const int tid = threadIdx.x;
    const int w = tid >> 6, lane = tid & 63;
    const int c = lane & 15, g = lane >> 4;
    const int m0 = (w & 1) * 64, n0 = (w >> 1) * 64;
#pragma unroll
    for (int mi = 0; mi < 4; ++mi) {
        int ocol = row0 + m0 + mi * 16 + g * 4;
        float4 bias = *(const float4*)&bp[ocol];
#pragma unroll
        for (int ni = 0; ni < 4; ++ni) {
            int p = col0 + n0 + ni * 16 + c;
            float4 u;
            u.x = acc[mi][ni][0] + bias.x;
            u.y = acc[mi][ni][1] + bias.y;
            u.z = acc[mi][ni][2] + bias.z;
            u.w = acc[mi][ni][3] + bias.w;
            *(float4*)&out[(size_t)p * 768 + ocol] = u;
        }
    }
}

// ---------------- bf16 MFMA flash attention ----------------------------------
// K from kb2 [b][kv][kt][d/8][key128][8], V from vb2 [b][kv][kt][key/8][d64][8]
// -> all fragment loads are coalesced 16B/lane runs.
#define LDP 136
__global__ __launch_bounds__(NTHREADS) void attn_mfma_k(
    const unsigned short* __restrict__ qbh, const unsigned short* __restrict__ kb2,
    const unsigned short* __restrict__ vb2, unsigned short* __restrict__ attb)
{
    __shared__ unsigned short P_lds[4 * 32 * LDP];
    __shared__ float alpha_s[4][32];
    __shared__ float l_s[4][32];

    const int qt0 = blockIdx.x * 128;
    const int h = blockIdx.y, b = blockIdx.z, kv = h >> 1;
    const int tid = threadIdx.x;
    const int w = tid >> 6, lane = tid & 63;
    const int c = lane & 15, g = lane >> 4;

    const unsigned short* qh = qbh + (((size_t)b * 12 + h) * 1024 + qt0 + w * 32) * 64;
    const unsigned short* kbase = kb2 + ((size_t)(b * 6 + kv) * 8) * 8192;
    const unsigned short* vbase = vb2 + ((size_t)(b * 6 + kv) * 8) * 8192;
    unsigned short* Pw = P_lds + w * 32 * LDP;

    f32x4 O[2][4];
#pragma unroll
    for (int i = 0; i < 2; ++i)
#pragma unroll
        for (int j = 0; j < 4; ++j) O[i][j] = (f32x4){0.f, 0.f, 0.f, 0.f};
    float m_r[2] = {-1e30f, -1e30f};
    float l_r[2] = {0.f, 0.f};

    for (int t = 0; t < 8; ++t) {
        const unsigned short* kt = kbase + (size_t)t * 8192;
        const unsigned short* vt = vbase + (size_t)t * 8192;
        f32x4 S[8][2];
#pragma unroll
        for (int mb = 0; mb < 8; ++mb) {
            S[mb][0] = (f32x4){0.f, 0.f, 0.f, 0.f};
            S[mb][1] = (f32x4){0.f, 0.f, 0.f, 0.f};
        }
#pragma unroll
        for (int ks = 0; ks < 2; ++ks) {
            bf16x8 bQ0 = *(const bf16x8*)(qh + (size_t)(c) * 64 + ks * 32 + g * 8);
            bf16x8 bQ1 = *(const bf16x8*)(qh + (size_t)(16 + c) * 64 + ks * 32 + g * 8);
#pragma unroll
            for (int mb = 0; mb < 8; ++mb) {
                bf16x8 aK = *(const bf16x8*)(kt + ((size_t)(ks * 4 + g) * 128 + mb * 16 + c) * 8);
                S[mb][0] = MFMA16(aK, bQ0, S[mb][0]);
                S[mb][1] = MFMA16(aK, bQ1, S[mb][1]);
            }
        }
#pragma unroll
        for (int qn = 0; qn < 2; ++qn) {
            float mt = -1e30f;
#pragma unroll
            for (int mb = 0; mb < 8; ++mb)
#pragma unroll
                for (int r = 0; r < 4; ++r) mt = fmaxf(mt, S[mb][qn][r]);
            mt = fmaxf(mt, __shfl_xor(mt, 16, 64));
            mt = fmaxf(mt, __shfl_xor(mt, 32, 64));
            float mnew = fmaxf(m_r[qn], mt);
            float alpha = __expf(m_r[qn] - mnew);
            float lt = 0.f;
#pragma unroll
            for (int mb = 0; mb < 8; ++mb) {
#pragma unroll
                for (int r = 0; r < 4; ++r) {
                    float p = __expf(S[mb][qn][r] - mnew);
                    S[mb][qn][r] = p;
                    lt += p;
                }
            }
            lt += __shfl_xor(lt, 16, 64);
            lt += __shfl_xor(lt, 32, 64);
            l_r[qn] = l_r[qn] * alpha + lt;
            m_r[qn] = mnew;
            if (g == 0) alpha_s[w][qn * 16 + c] = alpha;
#pragma unroll
            for (int mb = 0; mb < 8; ++mb) {
                uint2 uu;
                uu.x = pack_bf16x2(S[mb][qn][0], S[mb][qn][1]);
                uu.y = pack_bf16x2(S[mb][qn][2], S[mb][qn][3]);
                *(uint2*)&Pw[(size_t)(qn * 16 + c) * LDP + mb * 16 + g * 4] = uu;
            }
        }
        f32x4 al0 = *(f32x4*)&alpha_s[w][g * 4];
        f32x4 al1 = *(f32x4*)&alpha_s[w][16 + g * 4];
#pragma unroll
        for (int nb = 0; nb < 4; ++nb)
#pragma unroll
            for (int r = 0; r < 4; ++r) {
                O[0][nb][r] *= al0[r];
                O[1][nb][r] *= al1[r];
            }
#pragma unroll
        for (int ks = 0; ks < 4; ++ks) {
            bf16x8 aP0 = *(const bf16x8*)&Pw[(size_t)(c) * LDP + ks * 32 + g * 8];
            bf16x8 aP1 = *(const bf16x8*)&Pw[(size_t)(16 + c) * LDP + ks * 32 + g * 8];
#pragma unroll
            for (int nb = 0; nb < 4; ++nb) {
                bf16x8 bV = *(const bf16x8*)(vt + ((size_t)(ks * 4 + g) * 64 + nb * 16 + c) * 8);
                O[0][nb] = MFMA16(aP0, bV, O[0][nb]);
                O[1][nb] = MFMA16(aP1, bV, O[1][nb]);
            }
        }
    }
    if (g == 0) { l_s[w][c] = l_r[0]; l_s[w][16 + c] = l_r[1]; }
    f32x4 li0 = *(f32x4*)&l_s[w][g * 4];
    f32x4 li1 = *(f32x4*)&l_s[w][16 + g * 4];
    float inv0[4], inv1[4];
#pragma unroll
    for (int r = 0; r < 4; ++r) { inv0[r] = 1.f / li0[r]; inv1[r] = 1.f / li1[r]; }
    unsigned short* ob = attb + ((size_t)b * 1024 + qt0 + w * 32) * 768 + h * 64;
#pragma unroll
    for (int r = 0; r < 4; ++r) {
#pragma unroll
        for (int nb = 0; nb < 4; ++nb) {
            ob[(size_t)(g * 4 + r) * 768 + nb * 16 + c]      = bf16_rne(O[0][nb][r] * inv0[r]);
            ob[(size_t)(16 + g * 4 + r) * 768 + nb * 16 + c] = bf16_rne(O[1][nb][r] * inv1[r]);
        }
    }
}

// ---------------- per-(b,h) stats + noise subtraction (bf16 in/out) ----------
__global__ __launch_bounds__(NTHREADS) void stats_norm_k(
    unsigned short* __restrict__ attb, const float* __restrict__ zb)
{
    int bh = blockIdx.x;
    int b = bh / 12, h = bh % 12;
    unsigned short* base = attb + ((size_t)b * 1024) * 768 + h * 64;
    float sum = 0.f, sumsq = 0.f;
    for (int f = threadIdx.x; f < 8192; f += NTHREADS) {
        int p = f >> 3, dq = (f & 7) * 8;
        uint4 u = *(const uint4*)(base + (size_t)p * 768 + dq);
        float v0 = bfu(u.x), v1 = bfu(u.x >> 16);
        float v2 = bfu(u.y), v3 = bfu(u.y >> 16);
        float v4 = bfu(u.z), v5 = bfu(u.z >> 16);
        float v6 = bfu(u.w), v7 = bfu(u.w >> 16);
        sum   += (v0 + v1) + (v2 + v3) + (v4 + v5) + (v6 + v7);
        sumsq += (v0*v0 + v1*v1) + (v2*v2 + v3*v3) + (v4*v4 + v5*v5) + (v6*v6 + v7*v7);
    }
    __shared__ float rbuf[8];
    sum = wave_sum64(sum); sumsq = wave_sum64(sumsq);
    int lane = threadIdx.x & 63, wv = threadIdx.x >> 6;
    if (lane == 0) { rbuf[wv] = sum; rbuf[4 + wv] = sumsq; }
    __syncthreads();
    sum   = rbuf[0] + rbuf[1] + rbuf[2] + rbuf[3];
    sumsq = rbuf[4] + rbuf[5] + rbuf[6] + rbuf[7];
    float mean = sum * (1.f / 65536.f);
    float var  = (sumsq - 65536.f * mean * mean) * (1.f / 65535.f);
    float sd   = sqrtf(fmaxf(var, 0.f));
    const float* zrow = zb + (size_t)h * 65536;
    for (int f = threadIdx.x; f < 8192; f += NTHREADS) {
        int p = f >> 3, dq = (f & 7) * 8;
        unsigned short* ptr = base + (size_t)p * 768 + dq;
        uint4 u = *(const uint4*)ptr;
        const float* zp = zrow + (size_t)f * 8;
        float4 z0 = *(const float4*)zp;
        float4 z1 = *(const float4*)(zp + 4);
        float v0 = bfu(u.x)       - (z0.x * sd + mean);
        float v1 = bfu(u.x >> 16) - (z0.y * sd + mean);
        float v2 = bfu(u.y)       - (z0.z * sd + mean);
        float v3 = bfu(u.y >> 16) - (z0.w * sd + mean);
        float v4 = bfu(u.z)       - (z1.x * sd + mean);
        float v5 = bfu(u.z >> 16) - (z1.y * sd + mean);
        float v6 = bfu(u.w)       - (z1.z * sd + mean);
        float v7 = bfu(u.w >> 16) - (z1.w * sd + mean);
        uint4 o;
        o.x = pack_bf16x2(v0, v1);
        o.y = pack_bf16x2(v2, v3);
        o.z = pack_bf16x2(v4, v5);
        o.w = pack_bf16x2(v6, v7);
        *(uint4*)ptr = o;
    }
}

extern "C" void kernel_launch(void* const* d_in, const int* in_sizes, int n_in,
                              void* d_out, int out_size, void* d_ws, size_t ws_size,
                              hipStream_t stream) {
    const float* x  = (const float*)d_in[0];
    const float* Wq = (const float*)d_in[1];
    const float* Wk = (const float*)d_in[2];
    const float* Wv = (const float*)d_in[3];
    const float* Wp = (const float*)d_in[4];
    const float* bp = (const float*)d_in[5];
    float* out = (float*)d_out;

    float* ws    = (float*)d_ws;
    float* zb    = ws;                    // 786432 f
    float* zpart = zb + 786432;           // 192 f
    unsigned short* xb   = (unsigned short*)(zpart + 192);  // 6291456
    unsigned short* wqt  = xb + 6291456;   // 589824
    unsigned short* wkt  = wqt + 589824;   // 294912
    unsigned short* wvt  = wkt + 294912;   // 294912
    unsigned short* wpt  = wvt + 294912;   // 589824
    unsigned short* qbh  = wpt + 589824;   // 6291456
    unsigned short* kb2  = qbh + 6291456;  // 3145728
    unsigned short* vb2  = kb2 + 3145728;  // 3145728
    unsigned short* attb = vb2 + 3145728;  // 6291456

    z1_k<<<96, NTHREADS, 0, stream>>>(zb, zpart);
    z2_k<<<96, NTHREADS, 0, stream>>>(zb, zpart);
    cast_x_k<<<6144, NTHREADS, 0, stream>>>(x, xb);
    cast_w_k<<<432, NTHREADS, 0, stream>>>(Wq, Wk, Wv, Wp, wqt, wkt, wvt, wpt);
    qkv_mfma_k<<<dim3(12, 64), NTHREADS, 0, stream>>>(xb, wqt, wkt, wvt, qbh, kb2, vb2);
    attn_mfma_k<<<dim3(8, 12, 8), NTHREADS, 0, stream>>>(qbh, kb2, vb2, attb);
    stats_norm_k<<<96, NTHREADS, 0, stream>>>(attb, zb);
    proj_mfma_k<<<dim3(6, 64), NTHREADS, 0, stream>>>(attb, wpt, bp, out);
}